// Round 4
// baseline (789.672 us; speedup 1.0000x reference)
//
#include <hip/hip_runtime.h>

// GCN 2-layer: sigmoid( A_hat @ relu(A_hat @ (x@W1) + b1) @ W2 + b2 )
// A_hat = D^-1/2 (A + I) D^-1/2.
//
// Round 4:
//  - k_count   : 4 edges/thread, int4 nt loads, atomic count + pos capture
//  - k_scan    : single-kernel scan (98 co-resident blocks, sentinel bsum,
//                agent-scope atomics) + dis + W1->Bfrag prep (6 extra blocks)
//  - k_fillgemm: CSR fill blocks + MFMA gemm blocks fused in one dispatch;
//                gemm is 2-stage reg-pipelined, nontemporal x loads,
//                v_perm round-half-up bf16 pack; h1 rows 64-short aligned
//  - k_agg1    : wave/node gather (4 ways x 13 ch-lanes), fused bias/relu/W2
//  - k_agg2    : wave/node gather, fused bias/sigmoid

#define N_NODES 100000
#define N_EDGES 3200000
#define IN_DIM  768
#define HID     50
#define HIDP    64      // h1 row stride (shorts): 128B-aligned rows
#define HWID    52      // valid cols written/read (13 x ushort4)
#define SCAN_BLK 1024
#define NSCAN_BLKS 98   // 98*1024 = 100352 >= N_NODES
#define NPAD (NSCAN_BLKS * SCAN_BLK)
#define NKSTEP 24       // 768 / 32
#define GEMM_BLOCKS 782   // ceil(100000/128)
#define FILL_BLOCKS 3125  // 3.2M / (256*4)
#define WPREP_BLOCKS 6    // 24*256 jobs / 1024

using s8v = __attribute__((ext_vector_type(8))) short;   // 8 x bf16
using f4  = __attribute__((ext_vector_type(4))) float;
using u4  = __attribute__((ext_vector_type(4))) unsigned;
using i4  = __attribute__((ext_vector_type(4))) int;

// round-half-up bf16 pack: (u+0x8000)>>16, two at a time via v_perm
__device__ __forceinline__ unsigned pkbf(unsigned lo, unsigned hi) {
  return __builtin_amdgcn_perm(hi + 0x8000u, lo + 0x8000u, 0x07060302);
}
__device__ __forceinline__ s8v cvt8(f4 a, f4 b) {
  u4 ua = __builtin_bit_cast(u4, a), ub = __builtin_bit_cast(u4, b);
  u4 r;
  r[0] = pkbf(ua[0], ua[1]); r[1] = pkbf(ua[2], ua[3]);
  r[2] = pkbf(ub[0], ub[1]); r[3] = pkbf(ub[2], ub[3]);
  return __builtin_bit_cast(s8v, r);
}
__device__ __forceinline__ unsigned short f2bf_u(float f) {
  union { float f; unsigned u; } v; v.f = f;
  return (unsigned short)((v.u + 0x8000u) >> 16);
}
__device__ __forceinline__ float bf2f(unsigned short u) {
  union { unsigned u; float f; } v; v.u = ((unsigned)u) << 16;
  return v.f;
}

// ---------------- count + pos capture ----------------

__global__ __launch_bounds__(256) void k_count(const int* __restrict__ edges,
                                               int* __restrict__ cnt,
                                               int* __restrict__ pos) {
  int e0 = (blockIdx.x * 256 + threadIdx.x) * 4;
  i4 c = __builtin_nontemporal_load((const i4*)(edges + N_EDGES + e0));
  i4 p;
  p[0] = atomicAdd(&cnt[c[0]], 1);
  p[1] = atomicAdd(&cnt[c[1]], 1);
  p[2] = atomicAdd(&cnt[c[2]], 1);
  p[3] = atomicAdd(&cnt[c[3]], 1);
  __builtin_nontemporal_store(p, (i4*)(pos + e0));
}

// ---------------- fused scan (+dis) + wprep ----------------
// blocks [0,98): block-local scan, publish total to bsum[b] (sentinel -1),
// spin-read predecessors, write offs/dis. blocks [98,104): W1 -> Bfrag.

__global__ __launch_bounds__(1024) void k_scan(
    const int* __restrict__ cnt, int* __restrict__ offs,
    float* __restrict__ dis, int* __restrict__ bsum,
    const float* __restrict__ W1, short* __restrict__ Bfrag) {
  int b = blockIdx.x;
  int t = threadIdx.x;
  if (b >= NSCAN_BLKS) {
    // W1 -> B-fragment order: B[n=nt*16+(l&15)][k=s*32+(l>>4)*8+j]
    int g = (b - NSCAN_BLKS) * 1024 + t;   // < 6144
    int s = g >> 8, r = g & 255;
    int ct = r >> 6, l = r & 63;
    int n = ct * 16 + (l & 15);
    int kb = s * 32 + (l >> 4) * 8;
    s8v o;
#pragma unroll
    for (int j = 0; j < 8; ++j) {
      float w = (n < HID) ? W1[(size_t)(kb + j) * HID + n] : 0.f;
      o[j] = (short)f2bf_u(w);
    }
    *(s8v*)(Bfrag + (size_t)g * 8) = o;
    return;
  }
  __shared__ int s[SCAN_BLK];
  __shared__ int stot[128];
  int g = b * SCAN_BLK + t;
  int v = (g < N_NODES) ? cnt[g] : 0;
  s[t] = v;
  __syncthreads();
  for (int off = 1; off < SCAN_BLK; off <<= 1) {
    int add = (t >= off) ? s[t - off] : 0;
    __syncthreads();
    s[t] += add;
    __syncthreads();
  }
  if (t == SCAN_BLK - 1)
    __hip_atomic_store(&bsum[b], s[t], __ATOMIC_RELEASE, __HIP_MEMORY_SCOPE_AGENT);
  if (t < 128) {
    int pv = 0;
    if (t < b) {   // t < b <= 97
      do {
        pv = __hip_atomic_load(&bsum[t], __ATOMIC_ACQUIRE, __HIP_MEMORY_SCOPE_AGENT);
      } while (pv == -1);
    }
    stot[t] = pv;
  }
  for (int o = 64; o; o >>= 1) {
    __syncthreads();
    if (t < o) stot[t] += stot[t + o];
  }
  __syncthreads();
  int prefix = stot[0];
  offs[g] = prefix + s[t] - v;             // exclusive global
  if (g < N_NODES) dis[g] = rsqrtf((float)cnt[g] + 1.0f);
}

// ---------------- fused CSR fill + GEMM1 ----------------
// blocks [0,GEMM_BLOCKS): h1 = bf16((x@W1) * dis), rows 64-short stride.
// blocks [GEMM_BLOCKS, +FILL_BLOCKS): eidx[offs[c]+pos[e]] = row[e].

__global__ __launch_bounds__(256) void k_fillgemm(
    const float* __restrict__ x, const short* __restrict__ Bfrag,
    const float* __restrict__ dis, unsigned short* __restrict__ h1,
    const int* __restrict__ edges, const int* __restrict__ pos,
    const int* __restrict__ offs, int* __restrict__ eidx) {
  if (blockIdx.x >= GEMM_BLOCKS) {
    int e0 = ((blockIdx.x - GEMM_BLOCKS) * 256 + threadIdx.x) * 4;
    i4 r = __builtin_nontemporal_load((const i4*)(edges + e0));
    i4 c = __builtin_nontemporal_load((const i4*)(edges + N_EDGES + e0));
    i4 p = __builtin_nontemporal_load((const i4*)(pos + e0));
    eidx[offs[c[0]] + p[0]] = r[0];
    eidx[offs[c[1]] + p[1]] = r[1];
    eidx[offs[c[2]] + p[2]] = r[2];
    eidx[offs[c[3]] + p[3]] = r[3];
    return;
  }
  int t = threadIdx.x;
  int wave = t >> 6, lane = t & 63;
  int col = lane & 15, quad = lane >> 4;
  int rb = blockIdx.x * 128 + wave * 32;
  int ar0 = rb + col;       if (ar0 > N_NODES - 1) ar0 = N_NODES - 1;
  int ar1 = rb + 16 + col;  if (ar1 > N_NODES - 1) ar1 = N_NODES - 1;
  const float* xr0 = x + (size_t)ar0 * IN_DIM + quad * 8;
  const float* xr1 = x + (size_t)ar1 * IN_DIM + quad * 8;
  const short* bb = Bfrag + (size_t)lane * 8;

  f4 A[2][4]; s8v B[2][4];
  f4 acc[8] = {};

  A[0][0] = __builtin_nontemporal_load((const f4*)(xr0));
  A[0][1] = __builtin_nontemporal_load((const f4*)(xr0 + 4));
  A[0][2] = __builtin_nontemporal_load((const f4*)(xr1));
  A[0][3] = __builtin_nontemporal_load((const f4*)(xr1 + 4));
#pragma unroll
  for (int j = 0; j < 4; ++j) B[0][j] = *(const s8v*)(bb + (size_t)j * 512);

#pragma unroll
  for (int s = 0; s < NKSTEP; ++s) {
    int cur = s & 1, nxt = cur ^ 1;
    if (s + 1 < NKSTEP) {
      const float* p0 = xr0 + (s + 1) * 32;
      const float* p1 = xr1 + (s + 1) * 32;
      A[nxt][0] = __builtin_nontemporal_load((const f4*)p0);
      A[nxt][1] = __builtin_nontemporal_load((const f4*)(p0 + 4));
      A[nxt][2] = __builtin_nontemporal_load((const f4*)p1);
      A[nxt][3] = __builtin_nontemporal_load((const f4*)(p1 + 4));
#pragma unroll
      for (int j = 0; j < 4; ++j)
        B[nxt][j] = *(const s8v*)(bb + (size_t)((s + 1) * 4 + j) * 512);
    }
    s8v a0 = cvt8(A[cur][0], A[cur][1]);
    s8v a1 = cvt8(A[cur][2], A[cur][3]);
    acc[0] = __builtin_amdgcn_mfma_f32_16x16x32_bf16(a0, B[cur][0], acc[0], 0, 0, 0);
    acc[1] = __builtin_amdgcn_mfma_f32_16x16x32_bf16(a0, B[cur][1], acc[1], 0, 0, 0);
    acc[2] = __builtin_amdgcn_mfma_f32_16x16x32_bf16(a0, B[cur][2], acc[2], 0, 0, 0);
    acc[3] = __builtin_amdgcn_mfma_f32_16x16x32_bf16(a0, B[cur][3], acc[3], 0, 0, 0);
    acc[4] = __builtin_amdgcn_mfma_f32_16x16x32_bf16(a1, B[cur][0], acc[4], 0, 0, 0);
    acc[5] = __builtin_amdgcn_mfma_f32_16x16x32_bf16(a1, B[cur][1], acc[5], 0, 0, 0);
    acc[6] = __builtin_amdgcn_mfma_f32_16x16x32_bf16(a1, B[cur][2], acc[6], 0, 0, 0);
    acc[7] = __builtin_amdgcn_mfma_f32_16x16x32_bf16(a1, B[cur][3], acc[7], 0, 0, 0);
  }

  // C/D layout: col = lane&15, row = quad*4 + reg  [m89/m91]
#pragma unroll
  for (int half = 0; half < 2; ++half) {
    int node0 = rb + half * 16 + quad * 4;
    float dd[4];
#pragma unroll
    for (int r = 0; r < 4; ++r)
      dd[r] = (node0 + r < N_NODES) ? dis[node0 + r] : 0.f;
#pragma unroll
    for (int ct = 0; ct < 4; ++ct) {
      int c = ct * 16 + col;
      if (c < HWID) {
#pragma unroll
        for (int r = 0; r < 4; ++r) {
          int node = node0 + r;
          if (node < N_NODES)
            h1[((size_t)node << 6) + c] = f2bf_u(acc[half * 4 + ct][r] * dd[r]);
        }
      }
    }
  }
}

// ---------------- layer-1 aggregate + bias + relu + GEMM2 ----------------
// 1 wave per node: 4 edge-ways x 16 channel-lanes (13 active, 4 ch each).
// h1 rows pre-scaled by dis => plain gather-sum.

__global__ __launch_bounds__(256) void k_agg1(
    const unsigned short* __restrict__ h1, const int* __restrict__ eidx,
    const int* __restrict__ offs, const float* __restrict__ dis,
    const float* __restrict__ b1, const float* __restrict__ W2,
    float* __restrict__ h2s) {
  __shared__ float W2s[2][64];
  __shared__ float b1s[64];
  int t = threadIdx.x;
  if (t < 64) {
    b1s[t] = (t < HID) ? b1[t] : 0.f;
    W2s[0][t] = (t < HID) ? W2[t * 2 + 0] : 0.f;
    W2s[1][t] = (t < HID) ? W2[t * 2 + 1] : 0.f;
  }
  __syncthreads();
  int wave = t >> 6, lane = t & 63;
  int n = blockIdx.x * 4 + wave;
  if (n >= N_NODES) return;
  int way = lane >> 4, L = lane & 15;
  int base = L * 4;
  bool actC = base < HWID;           // 13 channel lanes active
  int baseS = actC ? base : 0;
  int start = offs[n];
  int end = offs[n + 1];

  float a0 = 0.f, a1 = 0.f, a2 = 0.f, a3 = 0.f;
  int i  = start + way;
  int idx  = (i  < end) ? __builtin_nontemporal_load(eidx + i)  : n;
  ushort4 u = *(const ushort4*)(h1 + ((size_t)idx << 6) + baseS);
  int i2 = i + 4;
  int idx2 = (i2 < end) ? __builtin_nontemporal_load(eidx + i2) : n;
  while (i < end) {
    ushort4 u2 = *(const ushort4*)(h1 + ((size_t)idx2 << 6) + baseS);
    int i3 = i2 + 4;
    int idx3 = (i3 < end) ? __builtin_nontemporal_load(eidx + i3) : n;
    a0 += bf2f(u.x); a1 += bf2f(u.y); a2 += bf2f(u.z); a3 += bf2f(u.w);
    u = u2; idx2 = idx3; i = i2; i2 = i3;
  }

  a0 += __shfl_xor(a0, 16); a0 += __shfl_xor(a0, 32);
  a1 += __shfl_xor(a1, 16); a1 += __shfl_xor(a1, 32);
  a2 += __shfl_xor(a2, 16); a2 += __shfl_xor(a2, 32);
  a3 += __shfl_xor(a3, 16); a3 += __shfl_xor(a3, 32);

  float p0 = 0.f, p1 = 0.f;
  if (actC && way == 0) {
    float dn = dis[n];
    ushort4 us = *(const ushort4*)(h1 + ((size_t)n << 6) + base);  // self
    float s0 = (a0 + bf2f(us.x)) * dn + b1s[base + 0];
    float s1 = (a1 + bf2f(us.y)) * dn + b1s[base + 1];
    float s2 = (a2 + bf2f(us.z)) * dn + b1s[base + 2];
    float s3 = (a3 + bf2f(us.w)) * dn + b1s[base + 3];
    s0 = fmaxf(s0, 0.f); s1 = fmaxf(s1, 0.f);
    s2 = fmaxf(s2, 0.f); s3 = fmaxf(s3, 0.f);
    p0 = s0 * W2s[0][base] + s1 * W2s[0][base + 1] +
         s2 * W2s[0][base + 2] + s3 * W2s[0][base + 3];
    p1 = s0 * W2s[1][base] + s1 * W2s[1][base + 1] +
         s2 * W2s[1][base + 2] + s3 * W2s[1][base + 3];
  }
  for (int m = 8; m; m >>= 1) {
    p0 += __shfl_xor(p0, m, 16);
    p1 += __shfl_xor(p1, m, 16);
  }
  if (lane == 0) {
    float dn = dis[n];
    h2s[(size_t)n * 2 + 0] = p0 * dn;   // pre-scale for layer 2
    h2s[(size_t)n * 2 + 1] = p1 * dn;
  }
}

// ---------------- layer-2 aggregate + bias + sigmoid ----------------

__global__ __launch_bounds__(256) void k_agg2(
    const float* __restrict__ h2s, const int* __restrict__ eidx,
    const int* __restrict__ offs, const float* __restrict__ dis,
    const float* __restrict__ b2, float* __restrict__ out) {
  int t = threadIdx.x;
  int wave = t >> 6, lane = t & 63;
  int n = blockIdx.x * 4 + wave;
  if (n >= N_NODES) return;
  int start = offs[n];
  int end = offs[n + 1];
  float s0 = 0.f, s1 = 0.f;
  for (int i = start + lane; i < end; i += 64) {
    int idx = __builtin_nontemporal_load(eidx + i);
    float2 v = *(const float2*)(h2s + (size_t)idx * 2);
    s0 += v.x; s1 += v.y;
  }
  for (int m = 32; m; m >>= 1) {
    s0 += __shfl_xor(s0, m);
    s1 += __shfl_xor(s1, m);
  }
  if (lane == 0) {
    float dn = dis[n];
    float2 v = *(const float2*)(h2s + (size_t)n * 2);
    float r0 = (s0 + v.x) * dn + b2[0];
    float r1 = (s1 + v.y) * dn + b2[1];
    out[(size_t)n * 2 + 0] = 1.f / (1.f + __expf(-r0));
    out[(size_t)n * 2 + 1] = 1.f / (1.f + __expf(-r1));
  }
}

// ---------------- launch ----------------

static inline size_t aln(size_t v) { return (v + 255) & ~(size_t)255; }

extern "C" void kernel_launch(void* const* d_in, const int* in_sizes, int n_in,
                              void* d_out, int out_size, void* d_ws, size_t ws_size,
                              hipStream_t stream) {
  const float* x     = (const float*)d_in[0];
  const int*   edges = (const int*)d_in[1];     // [2][E]: rows then cols
  const float* W1    = (const float*)d_in[2];   // [768][50]
  const float* b1    = (const float*)d_in[3];
  const float* W2    = (const float*)d_in[4];   // [50][2]
  const float* b2    = (const float*)d_in[5];
  float* out = (float*)d_out;

  char* p = (char*)d_ws;
  int* cnt  = (int*)p;            p += aln((size_t)NPAD * 4);
  int* offs = (int*)p;            p += aln((size_t)NPAD * 4);
  int* bsum = (int*)p;            p += aln((size_t)128 * 4);
  float* dis = (float*)p;         p += aln((size_t)N_NODES * 4);
  int* eidx = (int*)p;            p += aln((size_t)N_EDGES * 4);
  int* pos  = (int*)p;            p += aln((size_t)N_EDGES * 4);
  short* Bfrag = (short*)p;       p += aln((size_t)NKSTEP * 4 * 64 * 8 * 2);
  unsigned short* h1 = (unsigned short*)p; p += aln((size_t)N_NODES * HIDP * 2);
  float* h2s = (float*)p;         p += aln((size_t)N_NODES * 2 * 4);

  hipMemsetAsync(cnt, 0, (size_t)N_NODES * 4, stream);
  hipMemsetAsync(bsum, 0xFF, (size_t)NSCAN_BLKS * 4, stream);   // sentinel -1
  k_count<<<FILL_BLOCKS, 256, 0, stream>>>(edges, cnt, pos);
  k_scan<<<NSCAN_BLKS + WPREP_BLOCKS, SCAN_BLK, 0, stream>>>(cnt, offs, dis,
                                                             bsum, W1, Bfrag);
  k_fillgemm<<<GEMM_BLOCKS + FILL_BLOCKS, 256, 0, stream>>>(x, Bfrag, dis, h1,
                                                            edges, pos, offs, eidx);
  k_agg1<<<(N_NODES + 3) / 4, 256, 0, stream>>>(h1, eidx, offs, dis, b1, W2, h2s);
  k_agg2<<<(N_NODES + 3) / 4, 256, 0, stream>>>(h2s, eidx, offs, dis, b2, out);
}